// Round 1
// 63.467 us; speedup vs baseline: 1.0128x; 1.0128x over previous
//
#include <hip/hip_runtime.h>

// Problem constants: B=32, T=512, V=16, L=16, S=256, D=64, P=32
constexpr int Bc = 32;
constexpr int Tc = 512;
constexpr int Vc = 16;
constexpr int Lc = 16;
constexpr int Sc = 256;
constexpr int Dc = 64;
constexpr int Pc = 32;   // T / L

// One block per (b, v). 512 threads: thread pair (2t, 2t+1) owns shapelet s=t,
// each half covers patches of one parity -> half the serial hot-loop path of the
// 256-thread version, and 16 waves/CU instead of 8 for latency hiding.
// Distance via ||x||^2 + ||c||^2 - 2 x.c  -> 1 FMA/element in the hot loop.
__global__ __launch_bounds__(512, 4) void shapelet_fused_kernel(
    const float* __restrict__ x,      // [B, T, V]
    const float* __restrict__ cand,   // [V, S, L]
    const float* __restrict__ W,      // [S, D]
    const float* __restrict__ bias,   // [D]
    float* __restrict__ out)          // [B, D, V]
{
    // XCD-aware swizzle: 512 blocks, 8 XCDs -> logical chunk of 64 consecutive
    // blocks (4 full batches b, all 16 v each) per XCD, so the 16 v-blocks that
    // share x[b,:,:] cache lines hit the same L2.
    const int bid = blockIdx.x;
    const int lb  = ((bid & 7) << 6) | (bid >> 3);   // bijective: 512 % 8 == 0
    const int b   = lb >> 4;
    const int v   = lb & 15;

    const int tid = threadIdx.x;       // 0..511
    const int s   = tid >> 1;          // shapelet index (pair-shared)
    const int h   = tid & 1;           // patch parity handled by this thread

    __shared__ float xs[Tc];           // x[b, :, v], patch-major
    __shared__ float xnorm[Pc];        // per-patch ||x_p||^2
    __shared__ float soft[Sc];         // exp numerators
    __shared__ float rmax[8];
    __shared__ float rsum[8];
    __shared__ float pout[8][Dc];      // matmul partials (8 chunks of 32 s)

    // ---- stage x column v of batch b into LDS (1 load/thread) ----
    const float xv = x[(size_t)(b * Tc + tid) * Vc + v];
    xs[tid] = xv;

    // ---- candidate row s into registers (pair threads duplicate; L2-cheap) ----
    const float4* c4 = reinterpret_cast<const float4*>(cand + ((size_t)v * Sc + s) * Lc);
    const float4 ca = c4[0];
    const float4 cb = c4[1];
    const float4 cc = c4[2];
    const float4 cd = c4[3];

    // ---- W prefetch into registers: issued NOW so the cold-HBM latency hides
    // under the x/cand staging drain instead of serializing at the kernel tail.
    // thread (chunk, d): chunk = tid>>6 handles s in [chunk*32, chunk*32+32)
    const int d     = tid & 63;
    const int chunk = tid >> 6;
    const float* Wp = W + (size_t)(chunk * 32) * Dc + d;
    float w[32];
    #pragma unroll
    for (int i = 0; i < 32; ++i)
        w[i] = Wp[(size_t)i * Dc];

    // ---- per-patch ||x||^2 via 16-lane shuffle reduction ----
    float sq = xv * xv;
    #pragma unroll
    for (int off = 1; off < 16; off <<= 1)
        sq += __shfl_xor(sq, off);
    if ((tid & 15) == 0) xnorm[tid >> 4] = sq;

    // ---- ||c||^2 ----
    float cn;
    cn  = ca.x * ca.x; cn = fmaf(ca.y, ca.y, cn); cn = fmaf(ca.z, ca.z, cn); cn = fmaf(ca.w, ca.w, cn);
    cn = fmaf(cb.x, cb.x, cn); cn = fmaf(cb.y, cb.y, cn); cn = fmaf(cb.z, cb.z, cn); cn = fmaf(cb.w, cb.w, cn);
    cn = fmaf(cc.x, cc.x, cn); cn = fmaf(cc.y, cc.y, cn); cn = fmaf(cc.z, cc.z, cn); cn = fmaf(cc.w, cc.w, cn);
    cn = fmaf(cd.x, cd.x, cn); cn = fmaf(cd.y, cd.y, cn); cn = fmaf(cd.z, cd.z, cn); cn = fmaf(cd.w, cd.w, cn);

    __syncthreads();

    // ---- min over this thread's 16 patches (parity h) ----
    // dist = xnorm[p] + cn - 2 x.c ; cn added after the min.
    float dmin = 3.402823466e38f;
    #pragma unroll
    for (int i = 0; i < 16; ++i) {
        const int p = (i << 1) | h;
        const float4* xp = reinterpret_cast<const float4*>(xs + p * Lc);
        const float4 xa = xp[0];
        const float4 xb = xp[1];
        const float4 xc = xp[2];
        const float4 xd = xp[3];
        float dot;
        dot  = xa.x * ca.x;
        dot = fmaf(xa.y, ca.y, dot); dot = fmaf(xa.z, ca.z, dot); dot = fmaf(xa.w, ca.w, dot);
        dot = fmaf(xb.x, cb.x, dot); dot = fmaf(xb.y, cb.y, dot); dot = fmaf(xb.z, cb.z, dot); dot = fmaf(xb.w, cb.w, dot);
        dot = fmaf(xc.x, cc.x, dot); dot = fmaf(xc.y, cc.y, dot); dot = fmaf(xc.z, cc.z, dot); dot = fmaf(xc.w, cc.w, dot);
        dot = fmaf(xd.x, cd.x, dot); dot = fmaf(xd.y, cd.y, dot); dot = fmaf(xd.z, cd.z, dot); dot = fmaf(xd.w, cd.w, dot);
        dmin = fminf(dmin, fmaf(-2.0f, dot, xnorm[p]));
    }
    dmin += cn;
    // combine the two patch parities (pair lanes are adjacent -> same wave)
    dmin = fminf(dmin, __shfl_xor(dmin, 1));

    const int lane = tid & 63;
    const int wid  = tid >> 6;

    // ---- block max over dist (duplicates don't affect the max) ----
    float m = dmin;
    #pragma unroll
    for (int off = 32; off > 0; off >>= 1)
        m = fmaxf(m, __shfl_xor(m, off));
    if (lane == 0) rmax[wid] = m;
    __syncthreads();
    float blockmax = rmax[0];
    #pragma unroll
    for (int i = 1; i < 8; ++i) blockmax = fmaxf(blockmax, rmax[i]);

    // ---- exp + block sum (every s counted twice -> invsum = 2/total) ----
    const float e = __expf(dmin - blockmax);
    soft[s] = e;                       // pair threads write identical value
    float ssum = e;
    #pragma unroll
    for (int off = 32; off > 0; off >>= 1)
        ssum += __shfl_xor(ssum, off);
    if (lane == 0) rsum[wid] = ssum;
    __syncthreads();

    // ---- AR head: pout[chunk][d] = sum_{i<32} soft[chunk*32+i] * W[chunk*32+i][d]
    // soft reads are wave-uniform (chunk constant per wave) -> LDS broadcast.
    const float4* sp4 = reinterpret_cast<const float4*>(soft + chunk * 32);
    float acc0 = 0.0f, acc1 = 0.0f;
    #pragma unroll
    for (int j = 0; j < 8; ++j) {
        const float4 sv = sp4[j];
        acc0 = fmaf(sv.x, w[4 * j + 0], acc0);
        acc1 = fmaf(sv.y, w[4 * j + 1], acc1);
        acc0 = fmaf(sv.z, w[4 * j + 2], acc0);
        acc1 = fmaf(sv.w, w[4 * j + 3], acc1);
    }
    pout[chunk][d] = acc0 + acc1;
    __syncthreads();

    // ---- combine partials, normalize, bias, store ----
    if (tid < Dc) {
        float tot = rsum[0];
        #pragma unroll
        for (int i = 1; i < 8; ++i) tot += rsum[i];
        const float invsum = 2.0f / tot;   // each s summed twice above

        float r = pout[0][tid];
        #pragma unroll
        for (int c = 1; c < 8; ++c) r += pout[c][tid];

        out[(size_t)b * Dc * Vc + (size_t)tid * Vc + v] = fmaf(r, invsum, bias[tid]);
    }
}

extern "C" void kernel_launch(void* const* d_in, const int* in_sizes, int n_in,
                              void* d_out, int out_size, void* d_ws, size_t ws_size,
                              hipStream_t stream) {
    const float* x    = (const float*)d_in[0];   // [B, T, V]
    const float* cand = (const float*)d_in[1];   // [V, S, L]
    const float* W    = (const float*)d_in[2];   // [S, D]
    const float* bias = (const float*)d_in[3];   // [D]
    float* out = (float*)d_out;                  // [B, D, V]

    shapelet_fused_kernel<<<dim3(Bc * Vc), dim3(512), 0, stream>>>(x, cand, W, bias, out);
}